// Round 4
// baseline (374.570 us; speedup 1.0000x reference)
//
#include <hip/hip_runtime.h>
#include <hip/hip_bf16.h>

#define T_SEQ  2048
#define DMODEL 1024
#define NH     16
#define DH     64
#define NTOK   4096
// 0.125 * log2(e): fold softmax scale AND exp->exp2 conversion into Q
#define QSCALE 0.18033688011112042f

typedef unsigned short u16;
typedef short s16x8 __attribute__((ext_vector_type(8)));   // 8 bf16 raw bits (4 VGPRs)
typedef unsigned short u16x8 __attribute__((ext_vector_type(8)));
typedef float f32x4 __attribute__((ext_vector_type(4)));

__device__ __forceinline__ u16 f2bf(float f) {
  unsigned u = __float_as_uint(f);
  u += 0x7FFFu + ((u >> 16) & 1u);   // RNE
  return (u16)(u >> 16);
}
__device__ __forceinline__ unsigned pk2(float a, float b) {
  __hip_bfloat162 h = __float22bfloat162_rn(make_float2(a, b));
  unsigned u;
  __builtin_memcpy(&u, &h, 4);
  return u;
}
__device__ __forceinline__ float bf2f(u16 x) {
  return __uint_as_float(((unsigned)x) << 16);
}

// ---------------- cast fp32 -> bf16 ----------------
__global__ void cast_to_bf16(const float* __restrict__ in, u16* __restrict__ out, int n4) {
  int i = blockIdx.x * blockDim.x + threadIdx.x;
  if (i >= n4) return;
  float4 v = reinterpret_cast<const float4*>(in)[i];
  ushort4 r;
  r.x = f2bf(v.x); r.y = f2bf(v.y); r.z = f2bf(v.z); r.w = f2bf(v.w);
  reinterpret_cast<ushort4*>(out)[i] = r;
}

// ---------------- bf16 MFMA GEMM: C[M,N] = A[M,K]*B[N,K]^T (validated R2/R3) ----------------
template <int EPI>
__global__ __launch_bounds__(256) void gemm_bf16_nt(
    const u16* __restrict__ A, const u16* __restrict__ Bm,
    int M, int N, int K,
    u16* __restrict__ outQ, u16* __restrict__ outK,
    u16* __restrict__ outT, float* __restrict__ outF) {
  __shared__ __align__(16) u16 As[64][40];
  __shared__ __align__(16) u16 Bs[64][40];
  __shared__ __align__(16) u16 Cs[64][72];
  const int tid  = threadIdx.x;
  const int wave = tid >> 6;
  const int lane = tid & 63;
  const int bm = blockIdx.x * 64;
  const int bn = blockIdx.y * 64;

  f32x4 acc[4] = {};

  const int sr = tid >> 2;
  const int sk = (tid & 3) * 8;
  const u16* Ap = A  + (size_t)(bm + sr) * K + sk;
  const u16* Bp = Bm + (size_t)(bn + sr) * K + sk;

  const int frow = lane & 15;
  const int ko   = (lane >> 4) * 8;

  for (int k0 = 0; k0 < K; k0 += 32) {
    u16x8 av = *reinterpret_cast<const u16x8*>(Ap + k0);
    u16x8 bv = *reinterpret_cast<const u16x8*>(Bp + k0);
    *reinterpret_cast<u16x8*>(&As[sr][sk]) = av;
    *reinterpret_cast<u16x8*>(&Bs[sr][sk]) = bv;
    __syncthreads();
    s16x8 af = *reinterpret_cast<const s16x8*>(&As[wave * 16 + frow][ko]);
#pragma unroll
    for (int nt = 0; nt < 4; nt++) {
      s16x8 bf = *reinterpret_cast<const s16x8*>(&Bs[nt * 16 + frow][ko]);
      acc[nt] = __builtin_amdgcn_mfma_f32_16x16x32_bf16(af, bf, acc[nt], 0, 0, 0);
    }
    __syncthreads();
  }

  const int col = lane & 15;
  const int rb  = (lane >> 4) * 4;
  if (EPI == 2) {
#pragma unroll
    for (int nt = 0; nt < 4; nt++)
#pragma unroll
      for (int r = 0; r < 4; r++)
        outF[(size_t)(bm + wave * 16 + rb + r) * N + bn + nt * 16 + col] = acc[nt][r];
    return;
  }
  const float scale = (EPI == 0 && bn < 1024) ? QSCALE : 1.0f;
#pragma unroll
  for (int nt = 0; nt < 4; nt++)
#pragma unroll
    for (int r = 0; r < 4; r++)
      Cs[wave * 16 + rb + r][nt * 16 + col] = f2bf(acc[nt][r] * scale);
  __syncthreads();
  const int row = tid >> 2;
  const int seg = (tid & 3) * 16;
  u16x8 v0 = *reinterpret_cast<const u16x8*>(&Cs[row][seg]);
  u16x8 v1 = *reinterpret_cast<const u16x8*>(&Cs[row][seg + 8]);
  if (EPI == 0) {
    const int which = bn >> 10;
    const int h = (bn >> 6) & 15;
    u16* dst = (which ? outK : outQ) + ((size_t)h * NTOK + bm + row) * 64 + seg;
    *reinterpret_cast<u16x8*>(dst) = v0;
    *reinterpret_cast<u16x8*>(dst + 8) = v1;
  } else {
    u16* dst = outT + (size_t)(bm + row) * N + bn + seg;
    *reinterpret_cast<u16x8*>(dst) = v0;
    *reinterpret_cast<u16x8*>(dst + 8) = v1;
  }
}

// ---------------- attention kernel 1: row-max only ----------------
// Wave w owns j-strip [j0+16w,+16); Q in registers; K direct from global. No LDS in loop.
__global__ __launch_bounds__(256) void attn_max(
    const u16* __restrict__ Qb, const u16* __restrict__ Kb, float* __restrict__ Mrow) {
  __shared__ float Mb[4][64];
  const int tid = threadIdx.x, wave = tid >> 6, lane = tid & 63;
  const int f15 = lane & 15, quad = lane >> 4;
  const int y = blockIdx.y;
  const int b = y >> 4, h = y & 15;
  const int qt = (31 - (int)blockIdx.x + y) & 31;
  const int q0 = qt * 64;
  const size_t qk_base = ((size_t)h * NTOK + (size_t)b * T_SEQ) * 64;

  s16x8 qf[4][2];
#pragma unroll
  for (int nt = 0; nt < 4; nt++) {
    const u16* qp = Qb + qk_base + (size_t)(q0 + nt * 16 + f15) * 64 + quad * 8;
    qf[nt][0] = *reinterpret_cast<const s16x8*>(qp);
    qf[nt][1] = *reinterpret_cast<const s16x8*>(qp + 32);
  }
  const int jwf = wave * 16 + f15;       // A-frag row (j)
  const int jwq = wave * 16 + quad * 4;  // D rows (j) base
  float m_acc[4] = {-3.0e38f, -3.0e38f, -3.0e38f, -3.0e38f};

  for (int ti = 0; ti <= qt; ti++) {
    const int j0 = ti * 64;
    const u16* kp = Kb + qk_base + (size_t)(j0 + jwf) * 64 + quad * 8;
    s16x8 k0 = *reinterpret_cast<const s16x8*>(kp);
    s16x8 k1 = *reinterpret_cast<const s16x8*>(kp + 32);
    f32x4 accS[4] = {};
#pragma unroll
    for (int nt = 0; nt < 4; nt++) {
      accS[nt] = __builtin_amdgcn_mfma_f32_16x16x32_bf16(k0, qf[nt][0], accS[nt], 0, 0, 0);
      accS[nt] = __builtin_amdgcn_mfma_f32_16x16x32_bf16(k1, qf[nt][1], accS[nt], 0, 0, 0);
    }
    if (ti == qt) {
#pragma unroll
      for (int nt = 0; nt < 4; nt++) {
        const int mlim = nt * 16 + f15 - jwq;  // valid r <= mlim
#pragma unroll
        for (int r = 0; r < 4; r++)
          if (r > mlim) accS[nt][r] = -3.0e38f;
      }
    }
#pragma unroll
    for (int nt = 0; nt < 4; nt++) {
      float mx = fmaxf(fmaxf(accS[nt][0], accS[nt][1]), fmaxf(accS[nt][2], accS[nt][3]));
      m_acc[nt] = fmaxf(m_acc[nt], mx);
    }
  }
#pragma unroll
  for (int nt = 0; nt < 4; nt++) {
    float m = m_acc[nt];
    m = fmaxf(m, __shfl_xor(m, 16));
    m = fmaxf(m, __shfl_xor(m, 32));
    if (quad == 0) Mb[wave][nt * 16 + f15] = m;
  }
  __syncthreads();
  if (tid < 64) {
    float m = fmaxf(fmaxf(Mb[0][tid], Mb[1][tid]), fmaxf(Mb[2][tid], Mb[3][tid]));
    Mrow[(size_t)y * T_SEQ + q0 + tid] = m;
  }
}

// ---------------- attention kernel 2/3: PV with final m (no rescale) ----------------
// PASS=0: V=Vtb; computes l; stores AVt [d][tok] bf16 + AVq [tok][dmodel] bf16 + LinvG.
// PASS=1: V=AVt (normalized AV); epilogue TW = bf16(2*AVq - AAV).
// j-tiles processed in PAIRS so PV uses 16x16x32 with P fully in-lane (C-layout == B-layout).
template <int PASS>
__global__ __launch_bounds__(256, 3) void attn_pv(
    const u16* __restrict__ Qb, const u16* __restrict__ Kb, const u16* __restrict__ Vsrc,
    const float* __restrict__ Mrow, float* __restrict__ LinvG,
    u16* __restrict__ AVt, u16* __restrict__ AVq, u16* __restrict__ TW) {
  __shared__ __align__(16) float Obuf[3][64][68];   // merge buffers [q][d]
  __shared__ float Lbuf[4][64];
  __shared__ float Linv[64];
  const int tid = threadIdx.x, wave = tid >> 6, lane = tid & 63;
  const int f15 = lane & 15, quad = lane >> 4;
  const int y = blockIdx.y;
  const int b = y >> 4, h = y & 15;
  const int qt = (31 - (int)blockIdx.x + y) & 31;
  const int q0 = qt * 64;
  const size_t qk_base = ((size_t)h * NTOK + (size_t)b * T_SEQ) * 64;
  const size_t vt_base = (size_t)h * 64 * NTOK + (size_t)b * T_SEQ;

  s16x8 qf[4][2];
#pragma unroll
  for (int nt = 0; nt < 4; nt++) {
    const u16* qp = Qb + qk_base + (size_t)(q0 + nt * 16 + f15) * 64 + quad * 8;
    qf[nt][0] = *reinterpret_cast<const s16x8*>(qp);
    qf[nt][1] = *reinterpret_cast<const s16x8*>(qp + 32);
  }
  float m_q[4];
#pragma unroll
  for (int nt = 0; nt < 4; nt++)
    m_q[nt] = Mrow[(size_t)y * T_SEQ + q0 + nt * 16 + f15];

  f32x4 accO[4][4];  // [mt=d-tile][nt=q-tile]
#pragma unroll
  for (int mt = 0; mt < 4; mt++)
#pragma unroll
    for (int nt = 0; nt < 4; nt++) accO[mt][nt] = f32x4{0.f, 0.f, 0.f, 0.f};
  float l_acc[4] = {0.f, 0.f, 0.f, 0.f};

  const int jwf = wave * 16 + f15;
  const int jwq = wave * 16 + quad * 4;

  for (int ti = 0; ti <= qt; ti += 2) {
    const int tiA = ti, tiB = ti + 1;
    const bool hasB = (tiB <= qt);
    const int j0A = tiA * 64;
    const int j0B = hasB ? tiB * 64 : j0A;   // clamp for safe loads
    // --- issue all global loads up front ---
    const u16* kpA = Kb + qk_base + (size_t)(j0A + jwf) * 64 + quad * 8;
    const u16* kpB = Kb + qk_base + (size_t)(j0B + jwf) * 64 + quad * 8;
    s16x8 kA0 = *reinterpret_cast<const s16x8*>(kpA);
    s16x8 kA1 = *reinterpret_cast<const s16x8*>(kpA + 32);
    s16x8 kB0 = *reinterpret_cast<const s16x8*>(kpB);
    s16x8 kB1 = *reinterpret_cast<const s16x8*>(kpB + 32);
    union { s16x8 v; uint2 u[2]; } va[4];
#pragma unroll
    for (int mt = 0; mt < 4; mt++) {
      const u16* vp = Vsrc + vt_base + (size_t)(mt * 16 + f15) * NTOK;
      va[mt].u[0] = *reinterpret_cast<const uint2*>(vp + j0A + jwq);
      va[mt].u[1] = *reinterpret_cast<const uint2*>(vp + j0B + jwq);
    }
    // --- S^T tile A ---
    f32x4 accS[4] = {};
#pragma unroll
    for (int nt = 0; nt < 4; nt++) {
      accS[nt] = __builtin_amdgcn_mfma_f32_16x16x32_bf16(kA0, qf[nt][0], accS[nt], 0, 0, 0);
      accS[nt] = __builtin_amdgcn_mfma_f32_16x16x32_bf16(kA1, qf[nt][1], accS[nt], 0, 0, 0);
    }
    union { s16x8 v; unsigned u[4]; } pb[4];
    const bool maskA = (tiA == qt);
#pragma unroll
    for (int nt = 0; nt < 4; nt++) {
      float e0 = __builtin_amdgcn_exp2f(accS[nt][0] - m_q[nt]);
      float e1 = __builtin_amdgcn_exp2f(accS[nt][1] - m_q[nt]);
      float e2 = __builtin_amdgcn_exp2f(accS[nt][2] - m_q[nt]);
      float e3 = __builtin_amdgcn_exp2f(accS[nt][3] - m_q[nt]);
      if (maskA) {
        const int mlim = nt * 16 + f15 - jwq;
        if (0 > mlim) e0 = 0.f;
        if (1 > mlim) e1 = 0.f;
        if (2 > mlim) e2 = 0.f;
        if (3 > mlim) e3 = 0.f;
      }
      if (PASS == 0) l_acc[nt] += (e0 + e1) + (e2 + e3);
      pb[nt].u[0] = pk2(e0, e1);
      pb[nt].u[1] = pk2(e2, e3);
    }
    // --- S^T tile B ---
    if (hasB) {
#pragma unroll
      for (int nt = 0; nt < 4; nt++) {
        accS[nt] = f32x4{0.f, 0.f, 0.f, 0.f};
        accS[nt] = __builtin_amdgcn_mfma_f32_16x16x32_bf16(kB0, qf[nt][0], accS[nt], 0, 0, 0);
        accS[nt] = __builtin_amdgcn_mfma_f32_16x16x32_bf16(kB1, qf[nt][1], accS[nt], 0, 0, 0);
      }
      const bool maskB = (tiB == qt);
#pragma unroll
      for (int nt = 0; nt < 4; nt++) {
        float e0 = __builtin_amdgcn_exp2f(accS[nt][0] - m_q[nt]);
        float e1 = __builtin_amdgcn_exp2f(accS[nt][1] - m_q[nt]);
        float e2 = __builtin_amdgcn_exp2f(accS[nt][2] - m_q[nt]);
        float e3 = __builtin_amdgcn_exp2f(accS[nt][3] - m_q[nt]);
        if (maskB) {
          const int mlim = nt * 16 + f15 - jwq;
          if (0 > mlim) e0 = 0.f;
          if (1 > mlim) e1 = 0.f;
          if (2 > mlim) e2 = 0.f;
          if (3 > mlim) e3 = 0.f;
        }
        if (PASS == 0) l_acc[nt] += (e0 + e1) + (e2 + e3);
        pb[nt].u[2] = pk2(e0, e1);
        pb[nt].u[3] = pk2(e2, e3);
      }
    } else {
#pragma unroll
      for (int nt = 0; nt < 4; nt++) { pb[nt].u[2] = 0u; pb[nt].u[3] = 0u; }
    }
    // --- PV: accO[d][q] += V^T(pair) x P(pair), K=32, P fully in-lane ---
#pragma unroll
    for (int mt = 0; mt < 4; mt++)
#pragma unroll
      for (int nt = 0; nt < 4; nt++)
        accO[mt][nt] = __builtin_amdgcn_mfma_f32_16x16x32_bf16(va[mt].v, pb[nt].v, accO[mt][nt], 0, 0, 0);
  }

  // ---- merge across waves (one-time) ----
  if (PASS == 0) {
#pragma unroll
    for (int nt = 0; nt < 4; nt++) {
      float lr = l_acc[nt];
      lr += __shfl_xor(lr, 16);
      lr += __shfl_xor(lr, 32);
      if (quad == 0) Lbuf[wave][nt * 16 + f15] = lr;
    }
  }
  if (wave >= 1) {
#pragma unroll
    for (int mt = 0; mt < 4; mt++)
#pragma unroll
      for (int nt = 0; nt < 4; nt++)
        *reinterpret_cast<f32x4*>(&Obuf[wave - 1][nt * 16 + f15][mt * 16 + quad * 4]) = accO[mt][nt];
  }
  __syncthreads();
  if (wave == 0) {
#pragma unroll
    for (int w = 0; w < 3; w++)
#pragma unroll
      for (int mt = 0; mt < 4; mt++)
#pragma unroll
        for (int nt = 0; nt < 4; nt++)
          accO[mt][nt] += *reinterpret_cast<const f32x4*>(&Obuf[w][nt * 16 + f15][mt * 16 + quad * 4]);
#pragma unroll
    for (int mt = 0; mt < 4; mt++)
#pragma unroll
      for (int nt = 0; nt < 4; nt++)
        *reinterpret_cast<f32x4*>(&Obuf[0][nt * 16 + f15][mt * 16 + quad * 4]) = accO[mt][nt];
  } else if (PASS == 0 && wave == 1) {
    const int q = lane;
    float l = Lbuf[0][q] + Lbuf[1][q] + Lbuf[2][q] + Lbuf[3][q];
    float inv = 1.0f / l;
    Linv[q] = inv;
    LinvG[(size_t)y * T_SEQ + q0 + q] = inv;
  }
  __syncthreads();

  if (PASS == 0) {
    // AVt [h*64+d][tok] (transposed gather from Obuf) + AVq [tok][dmodel]
    {
      const int drow = tid >> 2, qseg = (tid & 3) * 16;
      u16x8 o0, o1;
#pragma unroll
      for (int i = 0; i < 8; i++) o0[i] = f2bf(Obuf[0][qseg + i][drow] * Linv[qseg + i]);
#pragma unroll
      for (int i = 0; i < 8; i++) o1[i] = f2bf(Obuf[0][qseg + 8 + i][drow] * Linv[qseg + 8 + i]);
      u16* dst = AVt + (size_t)(h * 64 + drow) * NTOK + (size_t)b * T_SEQ + q0 + qseg;
      *reinterpret_cast<u16x8*>(dst) = o0;
      *reinterpret_cast<u16x8*>(dst + 8) = o1;
    }
    {
      const int qrow = tid >> 2, dseg = (tid & 3) * 16;
      const float li = Linv[qrow];
      u16x8 o0, o1;
#pragma unroll
      for (int i = 0; i < 8; i++) o0[i] = f2bf(Obuf[0][qrow][dseg + i] * li);
#pragma unroll
      for (int i = 0; i < 8; i++) o1[i] = f2bf(Obuf[0][qrow][dseg + 8 + i] * li);
      u16* dst = AVq + ((size_t)b * T_SEQ + q0 + qrow) * DMODEL + h * 64 + dseg;
      *reinterpret_cast<u16x8*>(dst) = o0;
      *reinterpret_cast<u16x8*>(dst + 8) = o1;
    }
  } else {
    // TW = bf16(2*AVq - AAV)
    const int qrow = tid >> 2, dseg = (tid & 3) * 16;
    const float li = LinvG[(size_t)y * T_SEQ + q0 + qrow];
    const u16* avp = AVq + ((size_t)b * T_SEQ + q0 + qrow) * DMODEL + h * 64 + dseg;
    u16x8 a0 = *reinterpret_cast<const u16x8*>(avp);
    u16x8 a1 = *reinterpret_cast<const u16x8*>(avp + 8);
    u16x8 t0, t1;
#pragma unroll
    for (int i = 0; i < 8; i++)
      t0[i] = f2bf(2.0f * bf2f(a0[i]) - Obuf[0][qrow][dseg + i] * li);
#pragma unroll
    for (int i = 0; i < 8; i++)
      t1[i] = f2bf(2.0f * bf2f(a1[i]) - Obuf[0][qrow][dseg + 8 + i] * li);
    u16* dst = TW + ((size_t)b * T_SEQ + q0 + qrow) * DMODEL + h * 64 + dseg;
    *reinterpret_cast<u16x8*>(dst) = t0;
    *reinterpret_cast<u16x8*>(dst + 8) = t1;
  }
}

// ---------------- launch ----------------
extern "C" void kernel_launch(void* const* d_in, const int* in_sizes, int n_in,
                              void* d_out, int out_size, void* d_ws, size_t ws_size,
                              hipStream_t stream) {
  const float* x    = (const float*)d_in[0];
  const float* Wqkv = (const float*)d_in[1];
  const float* Wout = (const float*)d_in[2];
  float* out = (float*)d_out;
  char* ws = (char*)d_ws;

  u16*   Xb    = (u16*)(ws + 0);           //  8 MB  4096x1024 bf16
  u16*   Wqkvb = (u16*)(ws + 8388608);     //  6 MB
  u16*   Woutb = (u16*)(ws + 14680064);    //  2 MB
  u16*   Qb    = (u16*)(ws + 16777216);    //  8 MB  [h][token][64] (pre-scaled, log2e folded)
  u16*   Kb    = (u16*)(ws + 25165824);    //  8 MB  [h][token][64]
  u16*   Vtb   = (u16*)(ws + 33554432);    //  8 MB  [h*64+d][token]
  u16*   TW    = (u16*)(ws + 41943040);    //  8 MB  [token][1024]
  u16*   AVt   = (u16*)(ws + 50331648);    //  8 MB  [h*64+d][token] bf16 (normalized AV)
  u16*   AVq   = (u16*)(ws + 58720256);    //  8 MB  [token][1024] bf16
  float* Mrow  = (float*)(ws + 67108864);  // 256 KB (log2 domain row max)
  float* LinvG = (float*)(ws + 67371008);  // 256 KB (1/l)

  cast_to_bf16<<<4096, 256, 0, stream>>>(x, Xb, 1048576);
  cast_to_bf16<<<3072, 256, 0, stream>>>(Wqkv, Wqkvb, 786432);
  cast_to_bf16<<<1024, 256, 0, stream>>>(Wout, Woutb, 262144);

  gemm_bf16_nt<0><<<dim3(64, 32), 256, 0, stream>>>(Xb, Wqkvb, NTOK, 2048, DMODEL,
                                                    Qb, Kb, nullptr, nullptr);
  gemm_bf16_nt<1><<<dim3(16, 64), 256, 0, stream>>>(Wqkvb + 2048 * 1024, Xb, 1024, NTOK, DMODEL,
                                                    nullptr, nullptr, Vtb, nullptr);

  attn_max<<<dim3(32, 32), 256, 0, stream>>>(Qb, Kb, Mrow);
  attn_pv<0><<<dim3(32, 32), 256, 0, stream>>>(Qb, Kb, Vtb, Mrow, LinvG, AVt, AVq, nullptr);
  attn_pv<1><<<dim3(32, 32), 256, 0, stream>>>(Qb, Kb, AVt, Mrow, LinvG, nullptr, AVq, TW);

  gemm_bf16_nt<2><<<dim3(64, 16), 256, 0, stream>>>(TW, Woutb, NTOK, DMODEL, DMODEL,
                                                    nullptr, nullptr, nullptr, out);
}